// Round 13
// baseline (150.745 us; speedup 1.0000x reference)
//
#include <hip/hip_runtime.h>
#include <cstdint>
#include <cstddef>

#define BB 32
#define TT 14
#define DD 1024
#define RR 4
#define VV 8192
#define NCOL (VV*RR*RR)   // 131072 columns

typedef float f32x16 __attribute__((ext_vector_type(16)));
typedef float f4 __attribute__((ext_vector_type(4)));
typedef short short8 __attribute__((ext_vector_type(8)));
typedef unsigned int uint;

// ws layout (floats):
//  cm    : B*16   = 512   @ 0
//  sel   : B*T*16 = 7168  @ 512
//  alpha : B*4    = 128   @ 7680
//  beta  : B*4    = 128   @ 7808
//  xfrag : 8192 uint4     @ 7936   (A-fragments, bf16, 32 KB)

// pack hi16(a) | hi16(b)<<16  (bf16 truncation via byte-perm)
__device__ __forceinline__ uint pack2(float a, float b) {
    return __builtin_amdgcn_perm(__builtin_bit_cast(uint, b),
                                 __builtin_bit_cast(uint, a), 0x07060302u);
}

__device__ __forceinline__ short8 packw(const float* w) {
    uint4 u = make_uint4(pack2(w[0], w[1]), pack2(w[2], w[3]),
                         pack2(w[4], w[5]), pack2(w[6], w[7]));
    return __builtin_bit_cast(short8, u);
}

// One block per b: mean over T -> LDS; emit xfrag slice; alpha/beta dots; zero cm.
__global__ __launch_bounds__(256) void k_prep_all(const float* __restrict__ in,
                                                  const float* __restrict__ wa,
                                                  const float* __restrict__ wb,
                                                  ushort* __restrict__ xfrag_us,
                                                  float* __restrict__ alpha,
                                                  float* __restrict__ beta,
                                                  float* __restrict__ cm) {
    __shared__ float xl[DD];
    const int b   = blockIdx.x;
    const int tid = threadIdx.x;
    const int d0  = tid * 4;

    f4 s4 = (f4){0.f, 0.f, 0.f, 0.f};
    #pragma unroll
    for (int t = 0; t < TT; ++t) {
        f4 v = *reinterpret_cast<const f4*>(&in[((b * TT + t) << 10) + d0]);
        s4 += v;
    }
    s4 *= (1.0f / TT);
    *reinterpret_cast<f4*>(&xl[d0]) = s4;

    if (b == 0) { cm[tid] = 0.f; cm[tid + 256] = 0.f; }

    // xfrag: lane l = b + 32*h holds k = s*16 + h*8 + j  (j=0..7) of step s
    {
        const int s  = d0 >> 4;
        const int h  = (d0 >> 3) & 1;
        const int j0 = d0 & 7;           // 0 or 4
        uint2 u;
        u.x = pack2(s4.x, s4.y);
        u.y = pack2(s4.z, s4.w);
        *reinterpret_cast<uint2*>(&xfrag_us[((s * 64 + b + 32 * h) << 3) + j0]) = u;
    }

    __syncthreads();

    const int wave = tid >> 6, lane = tid & 63;
    for (int p = wave; p < 8; p += 4) {
        const int r = p >> 1, sf = p & 1;
        const float* wm = sf ? wb : wa;
        float acc = 0.f;
        #pragma unroll
        for (int k = 0; k < 16; ++k) {
            int d = lane + 64 * k;
            acc += xl[d] * wm[d * RR + r];
        }
        #pragma unroll
        for (int m = 1; m < 64; m <<= 1) acc += __shfl_xor(acc, m);
        if (lane == 0) {
            float v = 1.0f / (1.0f + __expf(-acc)) + 0.001f;
            (sf ? beta : alpha)[b * RR + r] = v;
        }
    }
}

// Load k-step STEP: 8 x dwordx4; lane gets 4 consecutive cols of 8 rows.
// Half-wave request = 512 B contiguous.
#define LOADW4(DST, STEP)                                                     \
    _Pragma("unroll")                                                         \
    for (int j = 0; j < 8; ++j)                                               \
        DST[j] = __builtin_nontemporal_load(reinterpret_cast<const f4*>(      \
            wp + (size_t)(16 * (STEP) + j) * NCOL));

// 4 MFMA tiles from one 8xf4 buffer: tile T uses element T of each load.
// Lane c's B-column for tile T is (4c + T) -- absorbed in epilogue indexing.
#define MFMA_T4(WB, AX)                                                       \
    _Pragma("unroll")                                                         \
    for (int tt = 0; tt < 4; ++tt) {                                          \
        float fr[8];                                                          \
        _Pragma("unroll")                                                     \
        for (int j = 0; j < 8; ++j) fr[j] = WB[j][tt];                        \
        acc[tt] = __builtin_amdgcn_mfma_f32_32x32x16_bf16(                    \
            __builtin_bit_cast(short8, AX), packw(fr), acc[tt], 0, 0, 0);     \
    }

// 256 blocks x 4 waves; wave owns 128 consecutive cols (4 permuted MFMA
// tiles, dwordx4 loads, no exchange). D: col=lane&31, b=(r&3)+8*(r>>2)+4*h.
__global__ __launch_bounds__(256) void k_core(const float* __restrict__ wv,
                                              const uint4* __restrict__ xfrag,
                                              const int*   __restrict__ lab,
                                              float* __restrict__ cm,
                                              float* __restrict__ sel) {
    const int tid  = threadIdx.x;
    const int lane = tid & 63;
    const int c    = lane & 31;
    const int h    = lane >> 5;
    const int w    = tid >> 6;                       // wave 0..3
    const int W    = blockIdx.x * 512 + w * 128;     // wave column base
    const int ii   = W >> 15;                        // r1 block (uniform)
    const int vb   = W >> 2;                         // vocab base for lane c

    __shared__ int   lds_lab[BB * TT];
    __shared__ float cm_blk[BB][4];

    const float* wp = wv + (size_t)(8 * h) * NCOL + W + 4 * c;

    f32x16 acc[4];
    #pragma unroll
    for (int t = 0; t < 4; ++t)
        #pragma unroll
        for (int q = 0; q < 16; ++q) acc[t][q] = 0.f;

    f4 wA[8], wB[8];
    uint4 axA, axB;
    LOADW4(wA, 0); axA = xfrag[lane];
    LOADW4(wB, 1); axB = xfrag[64 + lane];

    #pragma unroll 1
    for (int s = 0; s < 62; s += 2) {
        MFMA_T4(wA, axA);
        LOADW4(wA, s + 2); axA = xfrag[((s + 2) << 6) + lane];
        MFMA_T4(wB, axB);
        LOADW4(wB, s + 3); axB = xfrag[((s + 3) << 6) + lane];
    }
    MFMA_T4(wA, axA);
    MFMA_T4(wB, axB);

    // stage labels / zero block accumulator (kept out of the K-loop)
    for (int idx = tid; idx < BB * TT; idx += 256) lds_lab[idx] = lab[idx];
    if (tid < BB * 4) ((float*)cm_blk)[tid] = 0.f;
    __syncthreads();

    // epilogue: sigmoid, cm reduce, sel gather.
    // tile tt, lane c, reg r -> column W + 4c + tt: v = vb + c, j = tt.
    const int vv = vb + c;
    #pragma unroll
    for (int tt = 0; tt < 4; ++tt) {
        #pragma unroll
        for (int r = 0; r < 16; ++r) {
            float cval = 0.01f / (1.0f + __expf(-acc[tt][r])) + 0.001f;
            const int b = (r & 3) + 8 * (r >> 2) + 4 * h;
            float sred = cval;
            sred += __shfl_xor(sred, 1);
            sred += __shfl_xor(sred, 2);
            sred += __shfl_xor(sred, 4);
            sred += __shfl_xor(sred, 8);
            sred += __shfl_xor(sred, 16);
            if (c == 0) atomicAdd(&cm_blk[b][tt], sred);
            #pragma unroll
            for (int t = 0; t < TT; ++t)
                if (lds_lab[b * TT + t] == vv)
                    sel[(b * TT + t) * 16 + (ii << 2) + tt] = cval;
        }
    }
    __syncthreads();
    if (tid < BB * 4) {
        int b = tid >> 2, j = tid & 3;
        atomicAdd(&cm[b * 16 + (ii << 2) + j], ((float*)cm_blk)[tid]);
    }
}

__global__ __launch_bounds__(64) void k_final(const float* __restrict__ cm,
                                              const float* __restrict__ sel,
                                              const float* __restrict__ alpha,
                                              const float* __restrict__ beta,
                                              float* __restrict__ out) {
    __shared__ float ls[BB];
    int b = threadIdx.x;
    if (b < BB) {
        float ch[16], tmp[16];
        #pragma unroll
        for (int q = 0; q < 16; ++q) ch[q] = sel[(b * TT + 0) * 16 + q];
        for (int t = 1; t < TT; ++t) {
            const float* m = &sel[(b * TT + t) * 16];
            #pragma unroll
            for (int i2 = 0; i2 < 4; ++i2)
                #pragma unroll
                for (int j2 = 0; j2 < 4; ++j2) {
                    float s = 0.f;
                    #pragma unroll
                    for (int k = 0; k < 4; ++k) s += ch[i2*4+k] * m[k*4+j2];
                    tmp[i2*4+j2] = s;
                }
            #pragma unroll
            for (int q = 0; q < 16; ++q) ch[q] = tmp[q];
        }

        float M[16], P[16];
        #pragma unroll
        for (int q = 0; q < 16; ++q) { M[q] = cm[b*16+q]; P[q] = M[q]; }
        for (int t = 0; t < TT; ++t) {   // P = cm^(T+1)
            #pragma unroll
            for (int i2 = 0; i2 < 4; ++i2)
                #pragma unroll
                for (int j2 = 0; j2 < 4; ++j2) {
                    float s = 0.f;
                    #pragma unroll
                    for (int k = 0; k < 4; ++k) s += P[i2*4+k] * M[k*4+j2];
                    tmp[i2*4+j2] = s;
                }
            #pragma unroll
            for (int q = 0; q < 16; ++q) P[q] = tmp[q];
        }

        float a[4], be[4];
        #pragma unroll
        for (int r = 0; r < 4; ++r) { a[r] = alpha[b*4+r]; be[r] = beta[b*4+r]; }
        float un = 0.f, no = 0.f;
        #pragma unroll
        for (int i2 = 0; i2 < 4; ++i2)
            #pragma unroll
            for (int j2 = 0; j2 < 4; ++j2) {
                un += a[i2] * ch[i2*4+j2] * be[j2];
                no += a[i2] * P [i2*4+j2] * be[j2];
            }
        float prob = un / no + 0.001f;
        ls[b] = -logf(prob);
    }
    __syncthreads();
    if (threadIdx.x == 0) {
        float s = 0.f;
        for (int q = 0; q < BB; ++q) s += ls[q];
        out[0] = s / BB;
    }
}

extern "C" void kernel_launch(void* const* d_in, const int* in_sizes, int n_in,
                              void* d_out, int out_size, void* d_ws, size_t ws_size,
                              hipStream_t stream) {
    const float* in_embs = (const float*)d_in[0];
    const int*   lab     = (const int*)  d_in[1];
    const float* wa      = (const float*)d_in[2];
    const float* wb      = (const float*)d_in[3];
    const float* wv      = (const float*)d_in[4];

    float* ws    = (float*)d_ws;
    float* cm    = ws;
    float* sel   = ws + 512;
    float* alpha = ws + 7680;
    float* beta  = ws + 7808;
    uint4* xfrag = (uint4*)(ws + 7936);

    k_prep_all<<<32,  256, 0, stream>>>(in_embs, wa, wb, (ushort*)xfrag,
                                        alpha, beta, cm);
    k_core    <<<256, 256, 0, stream>>>(wv, xfrag, lab, cm, sel);
    k_final   <<<1,   64,  0, stream>>>(cm, sel, alpha, beta, (float*)d_out);
}

// Round 14
// 116.099 us; speedup vs baseline: 1.2984x; 1.2984x over previous
//
#include <hip/hip_runtime.h>
#include <cstdint>
#include <cstddef>

#define BB 32
#define TT 14
#define DD 1024
#define RR 4
#define VV 8192
#define NCOL (VV*RR*RR)   // 131072 columns

typedef float f32x16 __attribute__((ext_vector_type(16)));
typedef float f4 __attribute__((ext_vector_type(4)));
typedef short short8 __attribute__((ext_vector_type(8)));
typedef unsigned int uint;

// ws layout (floats):
//  cm    : B*16   = 512   @ 0
//  sel   : B*T*16 = 7168  @ 512
//  alpha : B*4    = 128   @ 7680
//  beta  : B*4    = 128   @ 7808
//  xfrag : 8192 uint4     @ 7936   (A-fragments, bf16, 32 KB)

// pack hi16(a) | hi16(b)<<16  (bf16 truncation via byte-perm)
__device__ __forceinline__ uint pack2(float a, float b) {
    return __builtin_amdgcn_perm(__builtin_bit_cast(uint, b),
                                 __builtin_bit_cast(uint, a), 0x07060302u);
}

__device__ __forceinline__ short8 packw(const float* w) {
    uint4 u = make_uint4(pack2(w[0], w[1]), pack2(w[2], w[3]),
                         pack2(w[4], w[5]), pack2(w[6], w[7]));
    return __builtin_bit_cast(short8, u);
}

// One block per b: mean over T -> LDS; emit xfrag slice; alpha/beta dots; zero cm.
__global__ __launch_bounds__(256) void k_prep_all(const float* __restrict__ in,
                                                  const float* __restrict__ wa,
                                                  const float* __restrict__ wb,
                                                  ushort* __restrict__ xfrag_us,
                                                  float* __restrict__ alpha,
                                                  float* __restrict__ beta,
                                                  float* __restrict__ cm) {
    __shared__ float xl[DD];
    const int b   = blockIdx.x;
    const int tid = threadIdx.x;
    const int d0  = tid * 4;

    f4 s4 = (f4){0.f, 0.f, 0.f, 0.f};
    #pragma unroll
    for (int t = 0; t < TT; ++t) {
        f4 v = *reinterpret_cast<const f4*>(&in[((b * TT + t) << 10) + d0]);
        s4 += v;
    }
    s4 *= (1.0f / TT);
    *reinterpret_cast<f4*>(&xl[d0]) = s4;

    if (b == 0) { cm[tid] = 0.f; cm[tid + 256] = 0.f; }

    // xfrag: lane l = b + 32*h holds k = s*16 + h*8 + j  (j=0..7) of step s
    {
        const int s  = d0 >> 4;
        const int h  = (d0 >> 3) & 1;
        const int j0 = d0 & 7;           // 0 or 4
        uint2 u;
        u.x = pack2(s4.x, s4.y);
        u.y = pack2(s4.z, s4.w);
        *reinterpret_cast<uint2*>(&xfrag_us[((s * 64 + b + 32 * h) << 3) + j0]) = u;
    }

    __syncthreads();

    const int wave = tid >> 6, lane = tid & 63;
    for (int p = wave; p < 8; p += 4) {
        const int r = p >> 1, sf = p & 1;
        const float* wm = sf ? wb : wa;
        float acc = 0.f;
        #pragma unroll
        for (int k = 0; k < 16; ++k) {
            int d = lane + 64 * k;
            acc += xl[d] * wm[d * RR + r];
        }
        #pragma unroll
        for (int m = 1; m < 64; m <<= 1) acc += __shfl_xor(acc, m);
        if (lane == 0) {
            float v = 1.0f / (1.0f + __expf(-acc)) + 0.001f;
            (sf ? beta : alpha)[b * RR + r] = v;
        }
    }
}

#define LOADW(DST, STEP)                                                      \
    _Pragma("unroll")                                                         \
    for (int j = 0; j < 8; ++j)                                               \
        DST[j] = __builtin_nontemporal_load(                                  \
            wp + (size_t)((STEP) * 16 + j) * NCOL);

// Wave owns 32 consecutive columns x all 32 b. One 32x32x16 MFMA per k-step.
// D mapping: col = lane&31, row(b) = (reg&3) + 8*(reg>>2) + 4*(lane>>5)
// __launch_bounds__(256,4): force VGPR<=128 -> 4 blocks/CU -> 4 waves/SIMD.
__global__ __launch_bounds__(256, 4) void k_core(const float* __restrict__ wv,
                                                 const uint4* __restrict__ xfrag,
                                                 const int*   __restrict__ lab,
                                                 float* __restrict__ cm,
                                                 float* __restrict__ sel) {
    const int tid  = threadIdx.x;
    const int lane = tid & 63;
    const int wvid = tid >> 6;                     // wave 0..3
    const int n0   = blockIdx.x * 128 + wvid * 32; // wave's column base
    const int n    = n0 + (lane & 31);
    const int ii   = n >> 15;                      // r1 block (uniform/block)
    const int jj   = n & 3;                        // r2
    const int vv   = (n >> 2) & (VV - 1);          // vocab index (per lane)

    __shared__ int   lds_lab[BB * TT];
    __shared__ float cm_blk[BB][4];

    const float* wp = wv + (size_t)((lane >> 5) * 8) * NCOL + n;

    f32x16 acc;
    #pragma unroll
    for (int q = 0; q < 16; ++q) acc[q] = 0.f;

    float w0[8], w1[8], w2[8], w3[8];
    uint4 ax0, ax1, ax2, ax3;
    LOADW(w0, 0); ax0 = xfrag[lane];
    LOADW(w1, 1); ax1 = xfrag[64 + lane];

    #pragma unroll 1
    for (int s = 0; s < 64; s += 4) {
        LOADW(w2, s + 2); ax2 = xfrag[((s + 2) << 6) + lane];
        LOADW(w3, s + 3); ax3 = xfrag[((s + 3) << 6) + lane];
        acc = __builtin_amdgcn_mfma_f32_32x32x16_bf16(
                  __builtin_bit_cast(short8, ax0), packw(w0), acc, 0, 0, 0);
        acc = __builtin_amdgcn_mfma_f32_32x32x16_bf16(
                  __builtin_bit_cast(short8, ax1), packw(w1), acc, 0, 0, 0);
        if (s + 4 < 64) {
            LOADW(w0, s + 4); ax0 = xfrag[((s + 4) << 6) + lane];
            LOADW(w1, s + 5); ax1 = xfrag[((s + 5) << 6) + lane];
        }
        acc = __builtin_amdgcn_mfma_f32_32x32x16_bf16(
                  __builtin_bit_cast(short8, ax2), packw(w2), acc, 0, 0, 0);
        acc = __builtin_amdgcn_mfma_f32_32x32x16_bf16(
                  __builtin_bit_cast(short8, ax3), packw(w3), acc, 0, 0, 0);
    }

    // stage labels / zero block-accumulator after the loop (barrier-free K-loop)
    for (int idx = tid; idx < BB * TT; idx += 256) lds_lab[idx] = lab[idx];
    if (tid < BB * 4) ((float*)cm_blk)[tid] = 0.f;
    __syncthreads();

    // epilogue: sigmoid, cm reduce, sel gather
    #pragma unroll
    for (int r = 0; r < 16; ++r) {
        float c = 0.01f / (1.0f + __expf(-acc[r])) + 0.001f;
        const int b = (r & 3) + 8 * (r >> 2) + 4 * (lane >> 5);
        float sred = c;
        sred += __shfl_xor(sred, 4);
        sred += __shfl_xor(sred, 8);
        sred += __shfl_xor(sred, 16);
        if ((lane & 31) < 4) atomicAdd(&cm_blk[b][lane & 3], sred);
        #pragma unroll
        for (int t = 0; t < TT; ++t)
            if (lds_lab[b * TT + t] == vv)
                sel[(b * TT + t) * 16 + (ii << 2) + jj] = c;
    }
    __syncthreads();
    if (tid < BB * 4) {
        int b = tid >> 2, j = tid & 3;
        atomicAdd(&cm[b * 16 + (ii << 2) + j], ((float*)cm_blk)[tid]);
    }
}

__global__ __launch_bounds__(64) void k_final(const float* __restrict__ cm,
                                              const float* __restrict__ sel,
                                              const float* __restrict__ alpha,
                                              const float* __restrict__ beta,
                                              float* __restrict__ out) {
    __shared__ float ls[BB];
    int b = threadIdx.x;
    if (b < BB) {
        float ch[16], tmp[16];
        #pragma unroll
        for (int q = 0; q < 16; ++q) ch[q] = sel[(b * TT + 0) * 16 + q];
        for (int t = 1; t < TT; ++t) {
            const float* m = &sel[(b * TT + t) * 16];
            #pragma unroll
            for (int i2 = 0; i2 < 4; ++i2)
                #pragma unroll
                for (int j2 = 0; j2 < 4; ++j2) {
                    float s = 0.f;
                    #pragma unroll
                    for (int k = 0; k < 4; ++k) s += ch[i2*4+k] * m[k*4+j2];
                    tmp[i2*4+j2] = s;
                }
            #pragma unroll
            for (int q = 0; q < 16; ++q) ch[q] = tmp[q];
        }

        float M[16], P[16];
        #pragma unroll
        for (int q = 0; q < 16; ++q) { M[q] = cm[b*16+q]; P[q] = M[q]; }
        for (int t = 0; t < TT; ++t) {   // P = cm^(T+1)
            #pragma unroll
            for (int i2 = 0; i2 < 4; ++i2)
                #pragma unroll
                for (int j2 = 0; j2 < 4; ++j2) {
                    float s = 0.f;
                    #pragma unroll
                    for (int k = 0; k < 4; ++k) s += P[i2*4+k] * M[k*4+j2];
                    tmp[i2*4+j2] = s;
                }
            #pragma unroll
            for (int q = 0; q < 16; ++q) P[q] = tmp[q];
        }

        float a[4], be[4];
        #pragma unroll
        for (int r = 0; r < 4; ++r) { a[r] = alpha[b*4+r]; be[r] = beta[b*4+r]; }
        float un = 0.f, no = 0.f;
        #pragma unroll
        for (int i2 = 0; i2 < 4; ++i2)
            #pragma unroll
            for (int j2 = 0; j2 < 4; ++j2) {
                un += a[i2] * ch[i2*4+j2] * be[j2];
                no += a[i2] * P [i2*4+j2] * be[j2];
            }
        float prob = un / no + 0.001f;
        ls[b] = -logf(prob);
    }
    __syncthreads();
    if (threadIdx.x == 0) {
        float s = 0.f;
        for (int q = 0; q < BB; ++q) s += ls[q];
        out[0] = s / BB;
    }
}

extern "C" void kernel_launch(void* const* d_in, const int* in_sizes, int n_in,
                              void* d_out, int out_size, void* d_ws, size_t ws_size,
                              hipStream_t stream) {
    const float* in_embs = (const float*)d_in[0];
    const int*   lab     = (const int*)  d_in[1];
    const float* wa      = (const float*)d_in[2];
    const float* wb      = (const float*)d_in[3];
    const float* wv      = (const float*)d_in[4];

    float* ws    = (float*)d_ws;
    float* cm    = ws;
    float* sel   = ws + 512;
    float* alpha = ws + 7680;
    float* beta  = ws + 7808;
    uint4* xfrag = (uint4*)(ws + 7936);

    k_prep_all<<<32,   256, 0, stream>>>(in_embs, wa, wb, (ushort*)xfrag,
                                         alpha, beta, cm);
    k_core    <<<1024, 256, 0, stream>>>(wv, xfrag, lab, cm, sel);
    k_final   <<<1,    64,  0, stream>>>(cm, sel, alpha, beta, (float*)d_out);
}